// Round 9
// baseline (162.820 us; speedup 1.0000x reference)
//
#include <hip/hip_runtime.h>
#include <hip/hip_bf16.h>
#include <cmath>

#define BDIM 8
#define HDIM 256
#define LDIM 4096
#define NDIM 64
#define TCH  64
#define NCH  64

typedef unsigned short u16;
typedef unsigned int   u32;
typedef __attribute__((ext_vector_type(8))) short short8x;
typedef __attribute__((ext_vector_type(4))) float f32x4;

__device__ __forceinline__ float rcp_fast(float x) { return __builtin_amdgcn_rcpf(x); }
__device__ __forceinline__ float tanh_fast(float x) {
    float e = __expf(2.0f * x);
    return 1.0f - 2.0f * rcp_fast(e + 1.0f);
}
__device__ __forceinline__ u16 f2bf(float f) {
    unsigned int u = __float_as_uint(f);
    u = u + 0x7fffu + ((u >> 16) & 1u);
    return (u16)(u >> 16);
}
__device__ __forceinline__ float bf2f(u16 s) {
    return __uint_as_float(((unsigned int)s) << 16);
}

// ---------------------------------------------------------------------------
// tables3: 4 waves per h; wave w handles t in [16w, 16w+16). Lane = n.
//  P_stack [128 n''][64 s] : [2n]=Re(Lam^{63-s}), [2n+1]=Im            (bf16 hi/lo)
//  G_stack [64 t][128 n''] : [2n]=2Re(CB Lam^{t+1}), [2n+1]=-2Im(...)  (bf16 hi/lo)
//  T       [64 t][64 s]    : K[t-s] (t>=s)                             (bf16 hi/lo)
//  L64     [n] = Lam_n^64                                              (f32)
// ---------------------------------------------------------------------------
__global__ __launch_bounds__(256) void tables3_kernel(
    const float* __restrict__ lre_g, const float* __restrict__ lim_g,
    const float* __restrict__ cbre_g, const float* __restrict__ cbim_g,
    u16* __restrict__ Phi, u16* __restrict__ Plo,
    u16* __restrict__ Ghi, u16* __restrict__ Glo,
    u16* __restrict__ Thi, u16* __restrict__ Tlo,
    float2* __restrict__ L64)
{
    __shared__ float Ksh[64];
    const int h = blockIdx.x;
    const int tid = threadIdx.x;
    const int w = tid >> 6;                 // t-block 0..3
    const int n = tid & 63;

    const float lr = lre_g[h * 64 + n], li = lim_g[h * 64 + n];
    const float cr = 2.0f * cbre_g[h * 64 + n];
    const float ci = 2.0f * cbim_g[h * 64 + n];

    u16* Ph = Phi + (size_t)h * 8192; u16* Pl = Plo + (size_t)h * 8192;
    u16* Gh = Ghi + (size_t)h * 8192; u16* Gl = Glo + (size_t)h * 8192;
    u16* Th = Thi + (size_t)h * 4096; u16* Tl = Tlo + (size_t)h * 4096;

    // s = Lam^16
    float sr = lr, si = li;
    #pragma unroll
    for (int j = 0; j < 4; ++j) {
        float tr = sr * sr - si * si;
        si = 2.0f * sr * si; sr = tr;
    }
    // q = Lam^{16w}
    float qr = 1.0f, qi = 0.0f;
    for (int j = 0; j < w; ++j) {
        float tr = qr * sr - qi * si;
        qi = qr * si + qi * sr; qr = tr;
    }

    #pragma unroll
    for (int j = 0; j < 16; ++j) {
        const int t = 16 * w + j;
        float kp = cr * qr - ci * qi;                // 2Re(CB Lam^t)
        #pragma unroll
        for (int m = 32; m > 0; m >>= 1) kp += __shfl_xor(kp, m);
        if (n == 0) Ksh[t] = kp;

        int sre = (2 * n) * 64 + (63 - t), sim = (2 * n + 1) * 64 + (63 - t);
        u16 hre = f2bf(qr); Ph[sre] = hre; Pl[sre] = f2bf(qr - bf2f(hre));
        u16 him = f2bf(qi); Ph[sim] = him; Pl[sim] = f2bf(qi - bf2f(him));

        float nqr = qr * lr - qi * li;               // Lam^{t+1}
        float nqi = qr * li + qi * lr;
        qr = nqr; qi = nqi;

        float gre = cr * qr - ci * qi;
        float gim = cr * qi + ci * qr;
        int o1 = t * 128 + 2 * n, o2 = o1 + 1;
        u16 g1 = f2bf(gre);  Gh[o1] = g1; Gl[o1] = f2bf(gre - bf2f(g1));
        float ngim = -gim;
        u16 g2 = f2bf(ngim); Gh[o2] = g2; Gl[o2] = f2bf(ngim - bf2f(g2));
    }
    if (w == 3) L64[h * 64 + n] = make_float2(qr, qi);   // Lam^64
    __syncthreads();

    const int r = tid >> 2, c0 = (tid & 3) * 16;
    #pragma unroll
    for (int i = 0; i < 16; ++i) {
        int c = c0 + i;
        float val = (c <= r) ? Ksh[r - c] : 0.0f;
        u16 hv = f2bf(val);
        Th[r * 64 + c] = hv; Tl[r * 64 + c] = f2bf(val - bf2f(hv));
    }
}

// ---------------------------------------------------------------------------
// scan7: one block per (b,h), 512 threads / 8 waves, ct-major tiling.
//  wave w: ct = w>>1 (16 chunks), mhalf = w&1.
//  V-phase : mi = 4*mhalf + 0..3  (16 A-loads -> 96 MFMA per wave)
//  chunk-scan: PARALLEL 3-stage (8-step local scan per wave-group of 8 chunks,
//              group totals, <=7-step offset, 8-step fixup). No 64-long serial.
//  Y-phase : mi = 2*mhalf + 0..1, same ct (U frags reused from V-phase).
// LDS: 73 rows x 512 B = 37376 B. V[c]@row c+1, X[c]@row c (hi|lo),
//      Y[c]@row c bytes 0..255 (over X-hi), t_g @ rows 65..72.
// ---------------------------------------------------------------------------
__global__ __launch_bounds__(512, 4) void scan7_kernel(
    const float* __restrict__ u,
    const float* __restrict__ Dg,
    const u16* __restrict__ Phi, const u16* __restrict__ Plo,
    const u16* __restrict__ Ghi, const u16* __restrict__ Glo,
    const u16* __restrict__ Thi, const u16* __restrict__ Tlo,
    const float2* __restrict__ L64g,
    float* __restrict__ y)
{
    __shared__ __align__(16) char smem[73 * 512];

    const int bid = blockIdx.x;
    const int b = bid >> 8;
    const int h = ((bid >> 3) & 31) * 8 + (bid & 7);   // same-h blocks share an XCD
    const int tid = threadIdx.x;
    const int w = tid >> 6, l = tid & 63;
    const int l15 = l & 15, lhi = l >> 4;
    const int ct = w >> 1;                 // this wave's column-tile (0..3)
    const int mhalf = w & 1;
    const int cB = 16 * ct + l15;          // this lane's chunk/column
    const int swX = (cB & 7) << 4;

    const float* urow = u + ((size_t)b * HDIM + h) * LDIM;

    // ---- U B-fragments for this wave's ct (reused in V and Y phases) ----
    short8x ubh[2], ubl[2];
    #pragma unroll
    for (int ks = 0; ks < 2; ++ks) {
        const float* src = urow + 64 * cB + 32 * ks + 8 * lhi;
        float4 f0 = *(const float4*)src;
        float4 f1 = *(const float4*)(src + 4);
        float fv[8] = {f0.x, f0.y, f0.z, f0.w, f1.x, f1.y, f1.z, f1.w};
        union { short8x v; u16 s[8]; } H, L;
        #pragma unroll
        for (int q = 0; q < 8; ++q) {
            u16 hq = f2bf(fv[q]);
            H.s[q] = hq; L.s[q] = f2bf(fv[q] - bf2f(hq));
        }
        ubh[ks] = H.v; ubl[ks] = L.v;
    }

    // ---- V = P_stack x U : mi = 4*mhalf + 0..3, this ct ----
    const u16* Ph = Phi + (size_t)h * 8192;
    const u16* Pl = Plo + (size_t)h * 8192;
    #pragma unroll
    for (int pair = 0; pair < 2; ++pair) {
        short8x pah[2][2], pal[2][2];
        #pragma unroll
        for (int m = 0; m < 2; ++m)
            #pragma unroll
            for (int ks = 0; ks < 2; ++ks) {
                int mi = 4 * mhalf + 2 * pair + m;
                int off = (16 * mi + l15) * 64 + 32 * ks + 8 * lhi;
                pah[m][ks] = *(const short8x*)(Ph + off);
                pal[m][ks] = *(const short8x*)(Pl + off);
            }
        #pragma unroll
        for (int m = 0; m < 2; ++m) {
            f32x4 a = {0.0f, 0.0f, 0.0f, 0.0f};
            #pragma unroll
            for (int ks = 0; ks < 2; ++ks) {
                a = __builtin_amdgcn_mfma_f32_16x16x32_bf16(pah[m][ks], ubh[ks], a, 0, 0, 0);
                a = __builtin_amdgcn_mfma_f32_16x16x32_bf16(pah[m][ks], ubl[ks], a, 0, 0, 0);
                a = __builtin_amdgcn_mfma_f32_16x16x32_bf16(pal[m][ks], ubh[ks], a, 0, 0, 0);
            }
            int mi = 4 * mhalf + 2 * pair + m;
            int rV = cB + 1;
            int byte = 512 * rV + 64 * mi + 16 * lhi;
            *(f32x4*)(smem + (byte ^ ((rV & 7) << 4))) = a;
        }
    }
    __syncthreads();                                   // B1: V complete

    // ---- parallel chunk-scan: group g = w, chunks a..a+7; lane = n ----
    {
        const int g = w, a = 8 * g;
        float2 lt = L64g[h * 64 + l];                  // Lam^64 per lane
        // prefetch this group's V
        float2 vv[8];
        #pragma unroll
        for (int j = 0; j < 8; ++j) {
            int r = a + j + 1;
            vv[j] = *(const float2*)(smem + ((512 * r + 8 * l) ^ ((r & 7) << 4)));
        }
        // local scan (start 0), record local prefixes l_j
        float ljr[8], lji[8];
        float xr = 0.0f, xi = 0.0f;
        #pragma unroll
        for (int j = 0; j < 8; ++j) {
            ljr[j] = xr; lji[j] = xi;
            float nr = fmaf(lt.x, xr, fmaf(-lt.y, xi, vv[j].x));
            float ni = fmaf(lt.x, xi, fmaf( lt.y, xr, vv[j].y));
            xr = nr; xi = ni;
        }
        // group total t_g -> LDS row 65+g
        {
            int r = 65 + g;
            *(float2*)(smem + ((512 * r + 8 * l) ^ ((r & 7) << 4))) = make_float2(xr, xi);
        }
        // L8 = Lam^512 per lane (3 squarings of Lam^64)
        float p8r = lt.x, p8i = lt.y;
        #pragma unroll
        for (int j = 0; j < 3; ++j) {
            float tr = p8r * p8r - p8i * p8i;
            p8i = 2.0f * p8r * p8i; p8r = tr;
        }
        __syncthreads();                               // B2: all t_g ready
        // exclusive group offset s_g
        float sr = 0.0f, si = 0.0f;
        for (int gp = 0; gp < g; ++gp) {
            int r = 65 + gp;
            float2 t = *(const float2*)(smem + ((512 * r + 8 * l) ^ ((r & 7) << 4)));
            float nsr = fmaf(p8r, sr, fmaf(-p8i, si, t.x));
            float nsi = fmaf(p8r, si, fmaf( p8i, sr, t.y));
            sr = nsr; si = nsi;
        }
        // fix-up: X[a+j] = Lam64^j * s_g + l_j, write bf16 hi/lo
        float pr = 1.0f, pi = 0.0f;
        #pragma unroll
        for (int j = 0; j < 8; ++j) {
            float Xr = fmaf(pr, sr, fmaf(-pi, si, ljr[j]));
            float Xi = fmaf(pr, si, fmaf( pi, sr, lji[j]));
            int c = a + j, sw = (c & 7) << 4;
            u16 hr = f2bf(Xr); u16 lr_ = f2bf(Xr - bf2f(hr));
            u16 hi_ = f2bf(Xi); u16 li_ = f2bf(Xi - bf2f(hi_));
            *(u32*)(smem + ((512 * c + 4 * l) ^ sw))       = (u32)hr  | ((u32)hi_ << 16);
            *(u32*)(smem + ((512 * c + 256 + 4 * l) ^ sw)) = (u32)lr_ | ((u32)li_ << 16);
            float npr = pr * lt.x - pi * lt.y;
            float npi = pr * lt.y + pi * lt.x;
            pr = npr; pi = npi;
        }
    }
    __syncthreads();                                   // B3: all X written

    // ---- Y-phase 6a: X B-frags for this ct (regs), then barrier ----
    short8x xbh[4], xbl[4];
    #pragma unroll
    for (int ks = 0; ks < 4; ++ks) {
        int byte = 512 * cB + 64 * ks + 16 * lhi;
        xbh[ks] = *(const short8x*)(smem + (byte ^ swX));
        xbl[ks] = *(const short8x*)(smem + ((byte + 256) ^ swX));
    }
    __syncthreads();                                   // B4: X reads done

    // ---- Y-phase 6b: mi = 2*mhalf + 0..1, Y = G x X + T x U ----
    const u16* Gh_ = Ghi + (size_t)h * 8192;
    const u16* Gl_ = Glo + (size_t)h * 8192;
    const u16* Th_ = Thi + (size_t)h * 4096;
    const u16* Tl_ = Tlo + (size_t)h * 4096;
    f32x4 yacc[2];
    #pragma unroll
    for (int m = 0; m < 2; ++m) {
        const int mi = 2 * mhalf + m;
        short8x gah[4], gal[4], tah[2], tal[2];
        #pragma unroll
        for (int ks = 0; ks < 4; ++ks) {
            int off = (16 * mi + l15) * 128 + 32 * ks + 8 * lhi;
            gah[ks] = *(const short8x*)(Gh_ + off);
            gal[ks] = *(const short8x*)(Gl_ + off);
        }
        #pragma unroll
        for (int ks = 0; ks < 2; ++ks) {
            int off = (16 * mi + l15) * 64 + 32 * ks + 8 * lhi;
            tah[ks] = *(const short8x*)(Th_ + off);
            tal[ks] = *(const short8x*)(Tl_ + off);
        }
        f32x4 a = {0.0f, 0.0f, 0.0f, 0.0f};
        #pragma unroll
        for (int ks = 0; ks < 4; ++ks) {
            a = __builtin_amdgcn_mfma_f32_16x16x32_bf16(gah[ks], xbh[ks], a, 0, 0, 0);
            a = __builtin_amdgcn_mfma_f32_16x16x32_bf16(gah[ks], xbl[ks], a, 0, 0, 0);
            a = __builtin_amdgcn_mfma_f32_16x16x32_bf16(gal[ks], xbh[ks], a, 0, 0, 0);
        }
        #pragma unroll
        for (int ks = 0; ks < 2; ++ks) {
            a = __builtin_amdgcn_mfma_f32_16x16x32_bf16(tah[ks], ubh[ks], a, 0, 0, 0);
            a = __builtin_amdgcn_mfma_f32_16x16x32_bf16(tah[ks], ubl[ks], a, 0, 0, 0);
            a = __builtin_amdgcn_mfma_f32_16x16x32_bf16(tal[ks], ubh[ks], a, 0, 0, 0);
        }
        yacc[m] = a;
    }
    #pragma unroll
    for (int m = 0; m < 2; ++m) {
        int mi = 2 * mhalf + m;
        int byte = 512 * cB + 64 * mi + 16 * lhi;      // Y[c][t] over X-hi
        *(f32x4*)(smem + (byte ^ swX)) = yacc[m];
    }
    __syncthreads();                                   // B5: Y complete

    // ---- epilogue: y = tanh(Y + D*u), 8 elems/thread ----
    const float Dh = Dg[h];
    float* yrow = y + ((size_t)b * HDIM + h) * LDIM;
    #pragma unroll
    for (int k = 0; k < 2; ++k) {
        int g4 = 2048 * k + 4 * tid;
        int c = g4 >> 6, t0 = g4 & 63;
        f32x4 yv = *(const f32x4*)(smem + ((512 * c + 4 * t0) ^ ((c & 7) << 4)));
        float4 uv = *(const float4*)(urow + g4);
        float4 o;
        o.x = tanh_fast(fmaf(Dh, uv.x, yv[0]));
        o.y = tanh_fast(fmaf(Dh, uv.y, yv[1]));
        o.z = tanh_fast(fmaf(Dh, uv.z, yv[2]));
        o.w = tanh_fast(fmaf(Dh, uv.w, yv[3]));
        *(float4*)(yrow + g4) = o;
    }
}

// ---------------------------------------------------------------------------
// W prep: Wp[r][h], r even -> W[r/2] (a-row), r odd -> W[r/2+256] (g-row);
// exact split into bf16 hi + lo, row-major [512][256].
// ---------------------------------------------------------------------------
__global__ __launch_bounds__(256) void prep_w(
    const float* __restrict__ W, u16* __restrict__ Wphi, u16* __restrict__ Wplo)
{
    const int r = blockIdx.x, hcol = threadIdx.x;
    const int src = (r & 1) ? (r >> 1) + 256 : (r >> 1);
    float v = W[src * 256 + hcol];
    u16 hv = f2bf(v);
    Wphi[r * 256 + hcol] = hv;
    Wplo[r * 256 + hcol] = f2bf(v - bf2f(hv));
}

// ---------------------------------------------------------------------------
// mix8: MFMA mix + GLU, BM=512 x BN=64, 512 threads / 8 waves (wave owns
// 64 rows = 4 mi x 4 ct). K=256 in 4 steps of 64, double-buffered Y staging.
// Grid 64 x 8 = 512 blocks = 2/CU. In-place safe: block owns its col-slice.
// ---------------------------------------------------------------------------
__global__ __launch_bounds__(512, 4) void mix8_kernel(
    const float* y,                        // d_out: scan output [B][256][4096]
    const u16* __restrict__ Wphi, const u16* __restrict__ Wplo,
    const float* __restrict__ bm,
    float* out)                            // d_out (aliases y)
{
    __shared__ __align__(16) u16 Ysh[2][64 * 64];   // 2 x 8 KB

    const int tid = threadIdx.x;
    const int w = tid >> 6, l = tid & 63;
    const int l15 = l & 15, lhi = l >> 4;
    const int b = blockIdx.y;
    const int col0 = blockIdx.x * 64;

    const float* Yb = y + ((size_t)b * HDIM) * LDIM;

    const int p  = tid >> 4;               // k-pair 0..31
    const int cg = tid & 15;               // col-group of 4

    f32x4 acc[4][4];                       // [mi][ct]
    #pragma unroll
    for (int mi = 0; mi < 4; ++mi)
        #pragma unroll
        for (int ct = 0; ct < 4; ++ct)
            acc[mi][ct] = (f32x4){0.0f, 0.0f, 0.0f, 0.0f};

    // ---- prologue: stage kb=0 into buf 0 ----
    {
        const float* r0 = Yb + (size_t)(2 * p) * LDIM + col0 + 4 * cg;
        float4 f0 = *(const float4*)r0;
        float4 f1 = *(const float4*)(r0 + LDIM);
        float f0v[4] = {f0.x, f0.y, f0.z, f0.w};
        float f1v[4] = {f1.x, f1.y, f1.z, f1.w};
        #pragma unroll
        for (int q = 0; q < 4; ++q) {
            int col = 4 * cg + q;
            u32 wv = (u32)f2bf(f0v[q]) | ((u32)f2bf(f1v[q]) << 16);
            int byte = (col * 128 + 4 * p) ^ ((col & 7) << 4);
            *(u32*)((char*)Ysh[0] + byte) = wv;
        }
    }
    __syncthreads();

    for (int kb = 0; kb < 4; ++kb) {
        const int k0 = kb * 64;
        const int cur = kb & 1;

        // ---- issue next K-tile's global loads EARLY ----
        float4 f0, f1;
        if (kb < 3) {
            const float* r0 = Yb + (size_t)(k0 + 64 + 2 * p) * LDIM + col0 + 4 * cg;
            f0 = *(const float4*)r0;
            f1 = *(const float4*)(r0 + LDIM);
        }

        // ---- compute on Ysh[cur]: 4 mi x 4 ct ----
        #pragma unroll
        for (int mi = 0; mi < 4; ++mi) {
            const size_t row = (size_t)(64 * w + 16 * mi + l15);
            short8x wh[2], wl[2];
            #pragma unroll
            for (int ks = 0; ks < 2; ++ks) {
                size_t off = row * 256 + k0 + 32 * ks + 8 * lhi;
                wh[ks] = *(const short8x*)(Wphi + off);
                wl[ks] = *(const short8x*)(Wplo + off);
            }
            #pragma unroll
            for (int ct = 0; ct < 4; ++ct) {
                #pragma unroll
                for (int ks = 0; ks < 2; ++ks) {
                    int col = 16 * ct + l15;
                    int byte = (col * 128 + 64 * ks + 16 * lhi) ^ ((col & 7) << 4);
                    short8x yb = *(const short8x*)((char*)Ysh[cur] + byte);
                    acc[mi][ct] = __builtin_amdgcn_mfma_f32_16x16x32_bf16(wh[ks], yb, acc[mi][ct], 0, 0, 0);
                    acc[mi][ct] = __builtin_amdgcn_mfma_f32_16x16x32_bf16(wl[ks], yb, acc[mi][ct], 0, 0, 0);
                }
            }
        }

        // ---- convert + write next buffer (disjoint from cur) ----
        if (kb < 3) {
            float f0v[4] = {f0.x, f0.y, f0.z, f0.w};
            float f1v[4] = {f1.x, f1.y, f1.z, f1.w};
            #pragma unroll
            for (int q = 0; q < 4; ++q) {
                int col = 4 * cg + q;
                u32 wv = (u32)f2bf(f0v[q]) | ((u32)f2bf(f1v[q]) << 16);
                int byte = (col * 128 + 4 * p) ^ ((col & 7) << 4);
                *(u32*)((char*)Ysh[cur ^ 1] + byte) = wv;
            }
        }
        __syncthreads();
    }

    // ---- epilogue: bias + GLU + store ----
    float* ob = out + ((size_t)b * HDIM) * LDIM;
    #pragma unroll
    for (int mi = 0; mi < 4; ++mi) {
        int r0 = 64 * w + 16 * mi + 4 * lhi;   // multiple of 4
        int h1 = r0 >> 1;
        float ba1 = bm[h1],     bg1 = bm[h1 + 256];
        float ba2 = bm[h1 + 1], bg2 = bm[h1 + 1 + 256];
        #pragma unroll
        for (int ct = 0; ct < 4; ++ct) {
            f32x4 a = acc[mi][ct];
            int col = col0 + 16 * ct + l15;
            float A1 = a[0] + ba1, G1 = a[1] + bg1;
            float A2 = a[2] + ba2, G2 = a[3] + bg2;
            ob[(size_t)h1 * LDIM + col]       = A1 * rcp_fast(1.0f + __expf(-G1));
            ob[(size_t)(h1 + 1) * LDIM + col] = A2 * rcp_fast(1.0f + __expf(-G2));
        }
    }
}

// ---------------------------------------------------------------------------
extern "C" void kernel_launch(void* const* d_in, const int* in_sizes, int n_in,
                              void* d_out, int out_size, void* d_ws, size_t ws_size,
                              hipStream_t stream)
{
    const float* u    = (const float*)d_in[0];
    const float* lre  = (const float*)d_in[1];
    const float* lim  = (const float*)d_in[2];
    const float* cbre = (const float*)d_in[3];
    const float* cbim = (const float*)d_in[4];
    const float* Dg   = (const float*)d_in[5];
    const float* W    = (const float*)d_in[6];
    const float* bm   = (const float*)d_in[7];
    float* out = (float*)d_out;

    char* ws = (char*)d_ws;
    size_t o = 0;
    u16* Wphi = (u16*)(ws + o); o += (size_t)1 << 18;      // 256 KB
    u16* Wplo = (u16*)(ws + o); o += (size_t)1 << 18;      // 256 KB
    u16* Phi = (u16*)(ws + o); o += (size_t)1 << 22;       // 4 MB each
    u16* Plo = (u16*)(ws + o); o += (size_t)1 << 22;
    u16* Ghi = (u16*)(ws + o); o += (size_t)1 << 22;
    u16* Glo = (u16*)(ws + o); o += (size_t)1 << 22;
    u16* Thi = (u16*)(ws + o); o += (size_t)1 << 21;       // 2 MB each
    u16* Tlo = (u16*)(ws + o); o += (size_t)1 << 21;
    float2* L64 = (float2*)(ws + o);                       // 128 KB

    tables3_kernel<<<HDIM, 256, 0, stream>>>(lre, lim, cbre, cbim,
                                             Phi, Plo, Ghi, Glo, Thi, Tlo, L64);
    prep_w<<<512, 256, 0, stream>>>(W, Wphi, Wplo);
    scan7_kernel<<<BDIM * HDIM, 512, 0, stream>>>(u, Dg, Phi, Plo, Ghi, Glo,
                                                  Thi, Tlo, L64, out);
    dim3 grid(LDIM / 64, BDIM);
    mix8_kernel<<<grid, 512, 0, stream>>>(out, Wphi, Wplo, bm, out);
}

// Round 10
// 100.231 us; speedup vs baseline: 1.6244x; 1.6244x over previous
//
#include <hip/hip_runtime.h>
#include <hip/hip_bf16.h>
#include <cmath>

#define BDIM 8
#define HDIM 256
#define LDIM 4096
#define NDIM 64
#define TCH  64
#define NCH  64

typedef unsigned short u16;
typedef unsigned int   u32;
typedef __attribute__((ext_vector_type(8))) short short8x;
typedef __attribute__((ext_vector_type(4))) float f32x4;

__device__ __forceinline__ float rcp_fast(float x) { return __builtin_amdgcn_rcpf(x); }
__device__ __forceinline__ float tanh_fast(float x) {
    float e = __expf(2.0f * x);
    return 1.0f - 2.0f * rcp_fast(e + 1.0f);
}
__device__ __forceinline__ u16 f2bf(float f) {
    unsigned int u = __float_as_uint(f);
    u = u + 0x7fffu + ((u >> 16) & 1u);
    return (u16)(u >> 16);
}
__device__ __forceinline__ float bf2f(u16 s) {
    return __uint_as_float(((unsigned int)s) << 16);
}

// ---------------------------------------------------------------------------
// tables4: 4 waves per h; wave w computes t in [16w,16w+16), lane = n.
// Lam^t staged in LDS [t][n] f32, then P dumped with COALESCED 16B stores
// (old P path was 2B stores at 128B stride = 64 transactions/instr).
// G packed as u32 (2 adjacent u16) per lane -> 256B contiguous per row.
// ---------------------------------------------------------------------------
__global__ __launch_bounds__(256) void tables4_kernel(
    const float* __restrict__ lre_g, const float* __restrict__ lim_g,
    const float* __restrict__ cbre_g, const float* __restrict__ cbim_g,
    u16* __restrict__ Phi, u16* __restrict__ Plo,
    u16* __restrict__ Ghi, u16* __restrict__ Glo,
    u16* __restrict__ Thi, u16* __restrict__ Tlo,
    float2* __restrict__ L64)
{
    __shared__ float qre[64][64];   // [t][n]
    __shared__ float qim[64][64];
    __shared__ float Ksh[64];
    const int h = blockIdx.x;
    const int tid = threadIdx.x;
    const int w = tid >> 6;                 // t-block 0..3
    const int n = tid & 63;

    const float lr = lre_g[h * 64 + n], li = lim_g[h * 64 + n];
    const float cr = 2.0f * cbre_g[h * 64 + n];
    const float ci = 2.0f * cbim_g[h * 64 + n];

    u32* Gh32 = (u32*)(Ghi + (size_t)h * 8192);
    u32* Gl32 = (u32*)(Glo + (size_t)h * 8192);
    u16* Th = Thi + (size_t)h * 4096; u16* Tl = Tlo + (size_t)h * 4096;

    // s = Lam^16
    float sr = lr, si = li;
    #pragma unroll
    for (int j = 0; j < 4; ++j) {
        float tr = sr * sr - si * si;
        si = 2.0f * sr * si; sr = tr;
    }
    // q = Lam^{16w}
    float qr = 1.0f, qi = 0.0f;
    for (int j = 0; j < w; ++j) {
        float tr = qr * sr - qi * si;
        qi = qr * si + qi * sr; qr = tr;
    }

    #pragma unroll
    for (int j = 0; j < 16; ++j) {
        const int t = 16 * w + j;
        float kp = cr * qr - ci * qi;                // 2Re(CB Lam^t)
        #pragma unroll
        for (int m = 32; m > 0; m >>= 1) kp += __shfl_xor(kp, m);
        if (n == 0) Ksh[t] = kp;

        qre[t][n] = qr; qim[t][n] = qi;              // Lam^t -> LDS

        float nqr = qr * lr - qi * li;               // Lam^{t+1}
        float nqi = qr * li + qi * lr;
        qr = nqr; qi = nqi;

        float gre = cr * qr - ci * qi;               // 2Re(CB Lam^{t+1})
        float gnim = -(cr * qi + ci * qr);           // -2Im(...)
        u16 g1h = f2bf(gre), g2h = f2bf(gnim);
        u16 g1l = f2bf(gre - bf2f(g1h)), g2l = f2bf(gnim - bf2f(g2h));
        Gh32[t * 64 + n] = (u32)g1h | ((u32)g2h << 16);
        Gl32[t * 64 + n] = (u32)g1l | ((u32)g2l << 16);
    }
    if (w == 3) L64[h * 64 + n] = make_float2(qr, qi);   // Lam^64
    __syncthreads();

    // ---- P dump (coalesced): thread -> row n''=tid>>1, half sh=(tid&1)*32 ----
    {
        const int row = tid >> 1;
        const int n0  = row >> 1;
        const float* src = (row & 1) ? &qim[0][0] : &qre[0][0];
        const int s0 = (tid & 1) * 32;
        union { u16 s[32]; short8x v[4]; } HB, LB;
        #pragma unroll
        for (int i = 0; i < 32; ++i) {
            int s = s0 + i;
            float v = src[(63 - s) * 64 + n0];       // Lam^{63-s}
            u16 hv = f2bf(v);
            HB.s[i] = hv; LB.s[i] = f2bf(v - bf2f(hv));
        }
        u16* dh = Phi + (size_t)h * 8192 + row * 64 + s0;
        u16* dl = Plo + (size_t)h * 8192 + row * 64 + s0;
        #pragma unroll
        for (int k2 = 0; k2 < 4; ++k2) {
            *(short8x*)(dh + 8 * k2) = HB.v[k2];
            *(short8x*)(dl + 8 * k2) = LB.v[k2];
        }
    }

    // ---- T build ----
    const int r = tid >> 2, c0 = (tid & 3) * 16;
    #pragma unroll
    for (int i = 0; i < 16; ++i) {
        int c = c0 + i;
        float val = (c <= r) ? Ksh[r - c] : 0.0f;
        u16 hv = f2bf(val);
        Th[r * 64 + c] = hv; Tl[r * 64 + c] = f2bf(val - bf2f(hv));
    }
}

// ---------------------------------------------------------------------------
// scan5b: scan5 tiling (measured best) + PARALLEL 4x16 chunk-scan + the
// X-read/Y-write split barrier. One block per (b,h), 4 waves.
// LDS: 69 rows x 512 B = 35328 B (V[c]@row c+1, X/Y[c]@row c, totals@65..68).
// ---------------------------------------------------------------------------
__global__ __launch_bounds__(256, 4) void scan5b_kernel(
    const float* __restrict__ u,
    const float* __restrict__ Dg,
    const u16* __restrict__ Phi, const u16* __restrict__ Plo,
    const u16* __restrict__ Ghi, const u16* __restrict__ Glo,
    const u16* __restrict__ Thi, const u16* __restrict__ Tlo,
    const float2* __restrict__ L64,
    float* __restrict__ y)
{
    __shared__ __align__(16) char smem[69 * 512];

    const int bid = blockIdx.x;
    const int b = bid >> 8;
    const int h = ((bid >> 3) & 31) * 8 + (bid & 7);   // same-h blocks share an XCD
    const int tid = threadIdx.x;
    const int w = tid >> 6, l = tid & 63;
    const int l15 = l & 15, lhi = l >> 4;

    const int ctBase  = (w & 1) * 2;
    const int miBaseV = (w >> 1) * 4;
    const int miBaseY = (w >> 1) * 2;

    const float* urow = u + ((size_t)b * HDIM + h) * LDIM;

    // ---- U B-fragments for this wave's 2 col-tiles, direct from global ----
    int cBt[2];
    short8x ubh[2][2], ubl[2][2];                      // [ct2][ks]
    #pragma unroll
    for (int ct2 = 0; ct2 < 2; ++ct2) {
        cBt[ct2] = 16 * (ctBase + ct2) + l15;
        #pragma unroll
        for (int ks = 0; ks < 2; ++ks) {
            const float* src = urow + 64 * cBt[ct2] + 32 * ks + 8 * lhi;
            float4 f0 = *(const float4*)src;
            float4 f1 = *(const float4*)(src + 4);
            float fv[8] = {f0.x, f0.y, f0.z, f0.w, f1.x, f1.y, f1.z, f1.w};
            union { short8x v; u16 s[8]; } H, L;
            #pragma unroll
            for (int q = 0; q < 8; ++q) {
                u16 hq = f2bf(fv[q]);
                H.s[q] = hq; L.s[q] = f2bf(fv[q] - bf2f(hq));
            }
            ubh[ct2][ks] = H.v; ubl[ct2][ks] = L.v;
        }
    }

    // ---- V = P_stack x U : 4 mi x 2 ct per wave ----
    const u16* Ph = Phi + (size_t)h * 8192;
    const u16* Pl = Plo + (size_t)h * 8192;
    {
        f32x4 acc[4][2];
        #pragma unroll
        for (int m = 0; m < 4; ++m)
            #pragma unroll
            for (int c2 = 0; c2 < 2; ++c2)
                acc[m][c2] = (f32x4){0.0f, 0.0f, 0.0f, 0.0f};

        #pragma unroll
        for (int pair = 0; pair < 2; ++pair) {
            short8x pah[2][2], pal[2][2];              // [m][ks]
            #pragma unroll
            for (int m = 0; m < 2; ++m)
                #pragma unroll
                for (int ks = 0; ks < 2; ++ks) {
                    int off = (16 * (miBaseV + 2 * pair + m) + l15) * 64 + 32 * ks + 8 * lhi;
                    pah[m][ks] = *(const short8x*)(Ph + off);
                    pal[m][ks] = *(const short8x*)(Pl + off);
                }
            #pragma unroll
            for (int m = 0; m < 2; ++m)
                #pragma unroll
                for (int ks = 0; ks < 2; ++ks)
                    #pragma unroll
                    for (int c2 = 0; c2 < 2; ++c2) {
                        f32x4 a = acc[2 * pair + m][c2];
                        a = __builtin_amdgcn_mfma_f32_16x16x32_bf16(pah[m][ks], ubh[c2][ks], a, 0, 0, 0);
                        a = __builtin_amdgcn_mfma_f32_16x16x32_bf16(pah[m][ks], ubl[c2][ks], a, 0, 0, 0);
                        a = __builtin_amdgcn_mfma_f32_16x16x32_bf16(pal[m][ks], ubh[c2][ks], a, 0, 0, 0);
                        acc[2 * pair + m][c2] = a;
                    }
        }
        #pragma unroll
        for (int m = 0; m < 4; ++m)
            #pragma unroll
            for (int c2 = 0; c2 < 2; ++c2) {
                int rV = cBt[c2] + 1;
                int byte = 512 * rV + 64 * (miBaseV + m) + 16 * lhi;
                *(f32x4*)(smem + (byte ^ ((rV & 7) << 4))) = acc[m][c2];
            }
    }
    __syncthreads();                                   // B1: V complete

    // ---- PARALLEL chunk-scan: wave g handles chunks 16g..16g+15, lane = n ----
    {
        const int g = w, a = 16 * g;
        float2 lt = L64[h * 64 + l];                   // Lam^64 per lane
        // prefetch this group's V into regs
        float2 vv[16];
        #pragma unroll
        for (int j = 0; j < 16; ++j) {
            int r = a + j + 1;
            vv[j] = *(const float2*)(smem + ((512 * r + 8 * l) ^ ((r & 7) << 4)));
        }
        // local scan from 0, recording local prefixes
        float ljr[16], lji[16];
        float xr = 0.0f, xi = 0.0f;
        #pragma unroll
        for (int j = 0; j < 16; ++j) {
            ljr[j] = xr; lji[j] = xi;
            float nr = fmaf(lt.x, xr, fmaf(-lt.y, xi, vv[j].x));
            float ni = fmaf(lt.x, xi, fmaf( lt.y, xr, vv[j].y));
            xr = nr; xi = ni;
        }
        // group total -> LDS row 65+g
        {
            int r = 65 + g;
            *(float2*)(smem + ((512 * r + 8 * l) ^ ((r & 7) << 4))) = make_float2(xr, xi);
        }
        // L16 = (Lam^64)^16 = Lam^1024
        float p16r = lt.x, p16i = lt.y;
        #pragma unroll
        for (int jj = 0; jj < 4; ++jj) {
            float tr = p16r * p16r - p16i * p16i;
            p16i = 2.0f * p16r * p16i; p16r = tr;
        }
        __syncthreads();                               // B2: totals ready
        // exclusive group offset s_g = sum_{g'<g} L16^{g-1-g'} t_{g'}
        float sr = 0.0f, si = 0.0f;
        for (int gp = 0; gp < g; ++gp) {
            int r = 65 + gp;
            float2 t = *(const float2*)(smem + ((512 * r + 8 * l) ^ ((r & 7) << 4)));
            float nsr = fmaf(p16r, sr, fmaf(-p16i, si, t.x));
            float nsi = fmaf(p16r, si, fmaf( p16i, sr, t.y));
            sr = nsr; si = nsi;
        }
        // fixup: X[a+j] = Lam64^j * s_g + l_j  (bf16 hi/lo to LDS)
        float pr = 1.0f, pi = 0.0f;
        #pragma unroll
        for (int j = 0; j < 16; ++j) {
            float Xr = fmaf(pr, sr, fmaf(-pi, si, ljr[j]));
            float Xi = fmaf(pr, si, fmaf( pi, sr, lji[j]));
            int c = a + j, sw2 = (c & 7) << 4;
            u16 hr2 = f2bf(Xr); u16 lr2 = f2bf(Xr - bf2f(hr2));
            u16 hi2 = f2bf(Xi); u16 li2 = f2bf(Xi - bf2f(hi2));
            *(u32*)(smem + ((512 * c + 4 * l) ^ sw2))       = (u32)hr2 | ((u32)hi2 << 16);
            *(u32*)(smem + ((512 * c + 256 + 4 * l) ^ sw2)) = (u32)lr2 | ((u32)li2 << 16);
            float npr = pr * lt.x - pi * lt.y;
            float npi = pr * lt.y + pi * lt.x;
            pr = npr; pi = npi;
        }
    }
    __syncthreads();                                   // B3: all X written

    // ---- X B-frags into regs, then split barrier (Y-write/X-read race fix) ----
    short8x xbh[2][4], xbl[2][4];                      // [ct2][ks]
    #pragma unroll
    for (int c2 = 0; c2 < 2; ++c2) {
        int swX = (cBt[c2] & 7) << 4;
        #pragma unroll
        for (int ks = 0; ks < 4; ++ks) {
            int byte = 512 * cBt[c2] + 64 * ks + 16 * lhi;
            xbh[c2][ks] = *(const short8x*)(smem + (byte ^ swX));
            xbl[c2][ks] = *(const short8x*)(smem + ((byte + 256) ^ swX));
        }
    }
    __syncthreads();                                   // B4: X reads done

    // ---- Y = G_stack x X + T x U : 2 mi x 2 ct per wave ----
    const u16* Gh_ = Ghi + (size_t)h * 8192;
    const u16* Gl_ = Glo + (size_t)h * 8192;
    const u16* Th_ = Thi + (size_t)h * 4096;
    const u16* Tl_ = Tlo + (size_t)h * 4096;
    #pragma unroll
    for (int m = 0; m < 2; ++m) {
        const int mi = miBaseY + m;
        f32x4 acc[2];
        acc[0] = (f32x4){0.0f, 0.0f, 0.0f, 0.0f};
        acc[1] = (f32x4){0.0f, 0.0f, 0.0f, 0.0f};
        short8x gah[4], gal[4], tah[2], tal[2];
        #pragma unroll
        for (int ks = 0; ks < 4; ++ks) {
            int off = (16 * mi + l15) * 128 + 32 * ks + 8 * lhi;
            gah[ks] = *(const short8x*)(Gh_ + off);
            gal[ks] = *(const short8x*)(Gl_ + off);
        }
        #pragma unroll
        for (int ks = 0; ks < 2; ++ks) {
            int off = (16 * mi + l15) * 64 + 32 * ks + 8 * lhi;
            tah[ks] = *(const short8x*)(Th_ + off);
            tal[ks] = *(const short8x*)(Tl_ + off);
        }
        #pragma unroll
        for (int ks = 0; ks < 4; ++ks)
            #pragma unroll
            for (int c2 = 0; c2 < 2; ++c2) {
                acc[c2] = __builtin_amdgcn_mfma_f32_16x16x32_bf16(gah[ks], xbh[c2][ks], acc[c2], 0, 0, 0);
                acc[c2] = __builtin_amdgcn_mfma_f32_16x16x32_bf16(gah[ks], xbl[c2][ks], acc[c2], 0, 0, 0);
                acc[c2] = __builtin_amdgcn_mfma_f32_16x16x32_bf16(gal[ks], xbh[c2][ks], acc[c2], 0, 0, 0);
            }
        #pragma unroll
        for (int ks = 0; ks < 2; ++ks)
            #pragma unroll
            for (int c2 = 0; c2 < 2; ++c2) {
                acc[c2] = __builtin_amdgcn_mfma_f32_16x16x32_bf16(tah[ks], ubh[c2][ks], acc[c2], 0, 0, 0);
                acc[c2] = __builtin_amdgcn_mfma_f32_16x16x32_bf16(tah[ks], ubl[c2][ks], acc[c2], 0, 0, 0);
                acc[c2] = __builtin_amdgcn_mfma_f32_16x16x32_bf16(tal[ks], ubh[c2][ks], acc[c2], 0, 0, 0);
            }
        #pragma unroll
        for (int c2 = 0; c2 < 2; ++c2) {
            int byte = 512 * cBt[c2] + 64 * mi + 16 * lhi;
            *(f32x4*)(smem + (byte ^ ((cBt[c2] & 7) << 4))) = acc[c2];
        }
    }
    __syncthreads();                                   // B5: Y complete

    // ---- epilogue: y = tanh(Y + D*u), vectorized x4 ----
    const float Dh = Dg[h];
    float* yrow = y + ((size_t)b * HDIM + h) * LDIM;
    #pragma unroll
    for (int k = 0; k < 4; ++k) {
        int g4 = 1024 * k + 4 * tid;
        int c = g4 >> 6, t0 = g4 & 63;
        f32x4 yv = *(const f32x4*)(smem + ((512 * c + 4 * t0) ^ ((c & 7) << 4)));
        float4 uv = *(const float4*)(urow + g4);
        float4 o;
        o.x = tanh_fast(fmaf(Dh, uv.x, yv[0]));
        o.y = tanh_fast(fmaf(Dh, uv.y, yv[1]));
        o.z = tanh_fast(fmaf(Dh, uv.z, yv[2]));
        o.w = tanh_fast(fmaf(Dh, uv.w, yv[3]));
        *(float4*)(yrow + g4) = o;
    }
}

// ---------------------------------------------------------------------------
// W prep: Wp[r][h], r even -> W[r/2] (a-row), r odd -> W[r/2+256] (g-row);
// exact split into bf16 hi + lo, row-major [512][256].
// ---------------------------------------------------------------------------
__global__ __launch_bounds__(256) void prep_w(
    const float* __restrict__ W, u16* __restrict__ Wphi, u16* __restrict__ Wplo)
{
    const int r = blockIdx.x, hcol = threadIdx.x;
    const int src = (r & 1) ? (r >> 1) + 256 : (r >> 1);
    float v = W[src * 256 + hcol];
    u16 hv = f2bf(v);
    Wphi[r * 256 + hcol] = hv;
    Wplo[r * 256 + hcol] = f2bf(v - bf2f(hv));
}

// ---------------------------------------------------------------------------
// mix7 (measured best): BM=512 x BN=128, 512 threads / 8 waves, K=256 in
// 4 steps, double-buffered Y staging, (512,2) so the compiler does NOT
// squeeze VGPRs (mix8's (512,4) caused a 58MB scratch-spill disaster).
// Grid 32 x 8 = 256 blocks. In-place on d_out (block-exclusive col slice).
// ---------------------------------------------------------------------------
__global__ __launch_bounds__(512, 2) void mix7_kernel(
    const float* y,                        // d_out: scan output [B][256][4096]
    const u16* __restrict__ Wphi, const u16* __restrict__ Wplo,
    const float* __restrict__ bm,
    float* out)                            // d_out (aliases y)
{
    __shared__ __align__(16) u16 Ysh[2][128 * 64];   // 2 x 16 KB

    const int tid = threadIdx.x;
    const int w = tid >> 6, l = tid & 63;
    const int l15 = l & 15, lhi = l >> 4;
    const int b = blockIdx.y;
    const int col0 = blockIdx.x * 128;

    const float* Yb = y + ((size_t)b * HDIM) * LDIM;

    const int p  = tid >> 4;               // k-pair 0..31
    const int cg = tid & 15;               // col-group of 8

    f32x4 acc[4][8];                       // [mi][ct]
    #pragma unroll
    for (int mi = 0; mi < 4; ++mi)
        #pragma unroll
        for (int ct = 0; ct < 8; ++ct)
            acc[mi][ct] = (f32x4){0.0f, 0.0f, 0.0f, 0.0f};

    // ---- prologue: stage kb=0 into buf 0 ----
    {
        const float* r0 = Yb + (size_t)(2 * p) * LDIM + col0 + 8 * cg;
        float4 a0 = *(const float4*)r0;
        float4 a1 = *(const float4*)(r0 + 4);
        float4 b0 = *(const float4*)(r0 + LDIM);
        float4 b1 = *(const float4*)(r0 + LDIM + 4);
        float f0v[8] = {a0.x, a0.y, a0.z, a0.w, a1.x, a1.y, a1.z, a1.w};
        float f1v[8] = {b0.x, b0.y, b0.z, b0.w, b1.x, b1.y, b1.z, b1.w};
        #pragma unroll
        for (int q = 0; q < 8; ++q) {
            int col = 8 * cg + q;
            u32 wv = (u32)f2bf(f0v[q]) | ((u32)f2bf(f1v[q]) << 16);
            int byte = (col * 128 + 4 * p) ^ ((col & 7) << 4);
            *(u32*)((char*)Ysh[0] + byte) = wv;
        }
    }
    __syncthreads();

    for (int kb = 0; kb < 4; ++kb) {
        const int k0 = kb * 64;
        const int cur = kb & 1;

        // ---- issue next K-tile's global loads EARLY ----
        float4 a0, a1, b0, b1;
        if (kb < 3) {
            const float* r0 = Yb + (size_t)(k0 + 64 + 2 * p) * LDIM + col0 + 8 * cg;
            a0 = *(const float4*)r0;
            a1 = *(const float4*)(r0 + 4);
            b0 = *(const float4*)(r0 + LDIM);
            b1 = *(const float4*)(r0 + LDIM + 4);
        }

        // ---- compute on Ysh[cur]: 4 mi x 8 ct ----
        #pragma unroll
        for (int mi = 0; mi < 4; ++mi) {
            const size_t row = (size_t)(64 * w + 16 * mi + l15);
            short8x wh[2], wl[2];
            #pragma unroll
            for (int ks = 0; ks < 2; ++ks) {
                size_t off = row * 256 + k0 + 32 * ks + 8 * lhi;
                wh[ks] = *(const short8x*)(Wphi + off);
                wl[ks] = *(const short8x*)(Wplo + off);
            }
            #pragma unroll
            for (int ct = 0; ct < 8; ++ct) {
                #pragma unroll
                for (int ks = 0; ks < 2; ++ks) {
                    int col = 16 * ct + l15;
                    int byte = (col * 128 + 64 * ks + 16 * lhi) ^ ((col & 7) << 4);
                    short8x yb = *(const short8x*)((char*)Ysh[cur] + byte);
                    acc[mi][ct] = __builtin_amdgcn_mfma_f32_16x16x32_bf16(wh[ks], yb, acc[mi][ct], 0, 0, 0);
                    acc[mi][ct] = __builtin_amdgcn_mfma_f32_16x16x32_bf16(wl[ks], yb, acc[mi][ct], 0, 0, 0);
                }
            }
        }

        // ---- convert + write next buffer (disjoint from cur) ----
        if (kb < 3) {
            float f0v[8] = {a0.x, a0.y, a0.z, a0.w, a1.x, a1.y, a1.z, a1.w};
            float f1v[8] = {b0.x, b0.y, b0.z, b0.w, b1.x, b1.y, b1.z, b1.w};
            #pragma unroll
            for (int q = 0; q < 8; ++q) {
                int col = 8 * cg + q;
                u32 wv = (u32)f2bf(f0v[q]) | ((u32)f2bf(f1v[q]) << 16);
                int byte = (col * 128 + 4 * p) ^ ((col & 7) << 4);
                *(u32*)((char*)Ysh[cur ^ 1] + byte) = wv;
            }
        }
        __syncthreads();
    }

    // ---- epilogue: bias + GLU + store ----
    float* ob = out + ((size_t)b * HDIM) * LDIM;
    #pragma unroll
    for (int mi = 0; mi < 4; ++mi) {
        int r0 = 64 * w + 16 * mi + 4 * lhi;   // multiple of 4
        int h1 = r0 >> 1;
        float ba1 = bm[h1],     bg1 = bm[h1 + 256];
        float ba2 = bm[h1 + 1], bg2 = bm[h1 + 1 + 256];
        #pragma unroll
        for (int ct = 0; ct < 8; ++ct) {
            f32x4 a = acc[mi][ct];
            int col = col0 + 16 * ct + l15;
            float A1 = a[0] + ba1, G1 = a[1] + bg1;
            float A2 = a[2] + ba2, G2 = a[3] + bg2;
            ob[(size_t)h1 * LDIM + col]       = A1 * rcp_fast(1.0f + __expf(-G1));
            ob[(size_t)(h1 + 1) * LDIM + col] = A2 * rcp_fast(1.0f + __expf(-G2));
        }
    }
}

// ---------------------------------------------------------------------------
extern "C" void kernel_launch(void* const* d_in, const int* in_sizes, int n_in,
                              void* d_out, int out_size, void* d_ws, size_t ws_size,
                              hipStream_t stream)
{
    const float* u    = (const float*)d_in[0];
    const float* lre  = (const float*)d_in[1];
    const float* lim  = (const float*)d_in[2];
    const float* cbre = (const float*)d_in[3];
    const float* cbim = (const float*)d_in[4];
    const float* Dg   = (const float*)d_in[5];
    const float* W    = (const float*)d_in[6];
    const float* bm   = (const float*)d_in[7];
    float* out = (float*)d_out;

    char* ws = (char*)d_ws;
    size_t o = 0;
    u16* Wphi = (u16*)(ws + o); o += (size_t)1 << 18;      // 256 KB
    u16* Wplo = (u16*)(ws + o); o += (size_t)1 << 18;      // 256 KB
    u16* Phi = (u16*)(ws + o); o += (size_t)1 << 22;       // 4 MB each
    u16* Plo = (u16*)(ws + o); o += (size_t)1 << 22;
    u16* Ghi = (u16*)(ws + o); o += (size_t)1 << 22;
    u16* Glo = (u16*)(ws + o); o += (size_t)1 << 22;
    u16* Thi = (u16*)(ws + o); o += (size_t)1 << 21;       // 2 MB each
    u16* Tlo = (u16*)(ws + o); o += (size_t)1 << 21;
    float2* L64 = (float2*)(ws + o);                       // 128 KB

    tables4_kernel<<<HDIM, 256, 0, stream>>>(lre, lim, cbre, cbim,
                                             Phi, Plo, Ghi, Glo, Thi, Tlo, L64);
    prep_w<<<512, 256, 0, stream>>>(W, Wphi, Wplo);
    scan5b_kernel<<<BDIM * HDIM, 256, 0, stream>>>(u, Dg, Phi, Plo, Ghi, Glo,
                                                   Thi, Tlo, L64, out);
    dim3 grid(LDIM / 128, BDIM);
    mix7_kernel<<<grid, 512, 0, stream>>>(out, Wphi, Wplo, bm, out);
}